// Round 9
// baseline (252.204 us; speedup 1.0000x reference)
//
#include <hip/hip_runtime.h>
#include <stdint.h>

#define DI 512
#define DH 512
#define DOUT 256
#define NB 32
#define NT 2048
#define MTOT (NB*NT)   // 65536
#define NCHUNK 16
#define CLEN 128       // NT / NCHUNK
#define BM 128
#define BN 64
#define BK 32

typedef unsigned short u16;
typedef __attribute__((ext_vector_type(8))) short bf16x8;
typedef __attribute__((ext_vector_type(4))) short s16x4;
typedef __attribute__((ext_vector_type(4))) float f32x4;

__device__ __forceinline__ u16 f2bf(float f) {
    union { float f; unsigned int u; } c; c.f = f;
    unsigned int u = c.u;
    u += 0x7fffu + ((u >> 16) & 1u);   // RNE
    return (u16)(u >> 16);
}
__device__ __forceinline__ float bf2f(u16 h) {
    union { unsigned int u; float f; } c; c.u = ((unsigned int)h) << 16;
    return c.f;
}
__device__ __forceinline__ float sigm(float x) { return 1.0f / (1.0f + __expf(-x)); }
__device__ __forceinline__ float tanh_(float x) { return 1.0f - 2.0f / (__expf(2.0f * x) + 1.0f); }

// ---------------- one-shot cvt: x (128MB) + 3 W matrices -> bf16 ----------------
// x: 8192 blocks x 256 thr x 2 iters (2x the waves of R8's 4096x4 for latency
// hiding on the 2-load/1-store stream). W: 768 extra blocks. Floor ~31us.
__global__ __launch_bounds__(256)
void cvt_all2(const float* __restrict__ X, const float* __restrict__ w0,
              const float* __restrict__ w1, const float* __restrict__ w2,
              u16* __restrict__ xbf, u16* __restrict__ wbf) {
    const int bid = blockIdx.x;
    const int tid = threadIdx.x;
    if (bid < 8192) {
        const int idx = bid * 256 + tid;           // 0..2097151
        const float4* s4 = reinterpret_cast<const float4*>(X);
        uint4* d4 = reinterpret_cast<uint4*>(xbf);
#pragma unroll
        for (int it = 0; it < 2; ++it) {
            const int j = it * 2097152 + idx;      // uint4 index < 4194304
            float4 v0 = s4[2 * j];
            float4 v1 = s4[2 * j + 1];
            unsigned int p0, p1, p2, p3;
            asm("v_cvt_pk_bf16_f32 %0, %1, %2" : "=v"(p0) : "v"(v0.x), "v"(v0.y));
            asm("v_cvt_pk_bf16_f32 %0, %1, %2" : "=v"(p1) : "v"(v0.z), "v"(v0.w));
            asm("v_cvt_pk_bf16_f32 %0, %1, %2" : "=v"(p2) : "v"(v1.x), "v"(v1.y));
            asm("v_cvt_pk_bf16_f32 %0, %1, %2" : "=v"(p3) : "v"(v1.z), "v"(v1.w));
            uint4 o; o.x = p0; o.y = p1; o.z = p2; o.w = p3;
            d4[j] = o;
        }
    } else {
        const int gid = (bid - 8192) * 256 + tid;  // 0..196607
        const int wsel = gid >> 16;                // per-W float4 count = 65536
        const int i = gid & 65535;
        const float* src = (wsel == 0) ? w0 : (wsel == 1) ? w1 : w2;
        float4 v = reinterpret_cast<const float4*>(src)[i];
        ushort4 o;
        o.x = f2bf(v.x); o.y = f2bf(v.y); o.z = f2bf(v.z); o.w = f2bf(v.w);
        reinterpret_cast<ushort4*>(wbf + (size_t)wsel * DH * DI)[i] = o;
    }
}

// ---------------- gate GEMM + activations + chunk scan (R8-proven, 121.4us) ----------------
// Only change vs R8: __launch_bounds__(256, 4) — occupancy probe. LDS 40960 x 4
// = exactly 160KiB; if the allocator packs 4 blocks/CU we gain 4 waves/CU of
// overlap; if LDS granularity rounds 40960 up (suspected ~48K -> 3 blocks),
// this is neutral (reg budget 4 waves/SIMD = 512/wave, no pressure at ~180).
__global__ __launch_bounds__(256, 4)
void gate_gemm_scan(const u16* __restrict__ Xbf, const u16* __restrict__ W,
                    const float* __restrict__ b_i, const float* __restrict__ b_f,
                    const float* __restrict__ b_g,
                    float* __restrict__ Ach, float* __restrict__ Vch) {
    __shared__ __align__(16) union {
        struct { u16 sA[2][BM * BK]; u16 sB[2][3 * BN * BK]; } st;   // 16KB + 24KB = 40KB
        struct { u16 Ft[BN][132]; u16 Pt[BN][132]; float pa[256]; float pv[256]; } sc;
    } u;

    // XCD-aware swizzle: blocks with bid%8==k land on XCD k and cover one
    // mtile's 8 ntiles consecutively -> A L2-shared within the XCD.
    const int bid0 = blockIdx.x;
    const int swz = (bid0 & 7) * 512 + (bid0 >> 3);
    const int mtile = swz >> 3;          // 0..511  (b*16 + chunk)
    const int ntile = swz & 7;           // 0..7
    const int m0 = mtile * BM;
    const int n0 = ntile * BN;

    const int tid = threadIdx.x;
    const int lane = tid & 63;
    const int ws = __builtin_amdgcn_readfirstlane(tid >> 6);   // scalar wave id
    const int wr = ws >> 1;              // M offset wr*64
    const int wc = ws & 1;               // N offset wc*32

    const int srow = lane >> 2;          // staging: row within 16-row chunk
    const int slot = lane & 3;           // staging: 16B slot within 64B row
    const int fr = lane & 15;
    const int khalf = lane >> 4;         // 0..3

    // A bf16 source: pre-swizzled per-lane addr; LDS image matches the proven
    // swizzled layout, so frag reads are unchanged.
    const int rlA = ws * 32 + srow;
    const int swzslot = slot ^ ((rlA >> 1) & 3);       // same for row+16
    const u16* pA0 = Xbf + (size_t)(m0 + rlA) * DI + swzslot * 8;
    const u16* pA1 = pA0 + (size_t)16 * DI;

    // B staging base (q=0) + wave-uniform deltas for q=1,2 (proven).
    const int idx0 = ws * 3;
    const int g0 = idx0 >> 2, cc0 = idx0 & 3;
    const int rlB0 = cc0 * 16 + srow;
    const u16* gaB0 = W + (size_t)g0 * DH * DI + (size_t)(n0 + rlB0) * DI
                    + ((slot ^ ((rlB0 >> 1) & 3)) * 8);
    int dB[3];
    dB[0] = 0;
#pragma unroll
    for (int q = 1; q < 3; ++q) {
        const int idxq = idx0 + q;
        const int gq = idxq >> 2, ccq = idxq & 3;
        dB[q] = __builtin_amdgcn_readfirstlane((gq - g0) * (DH * DI) + (ccq - cc0) * 16 * DI);
    }

    // per-lane LDS read offsets (u16 units), swizzled slot (proven, 0-conflict)
    const int rA = wr * 64 + fr;
    const int offA0 = rA * BK + ((khalf ^ ((rA >> 1) & 3)) * 8);
    const int rB = wc * 32 + fr;
    const int offB0 = rB * BK + ((khalf ^ ((rB >> 1) & 3)) * 8);

#define STAGE_A(CB, KT) do {                                                        \
    u16* sAb = u.st.sA[(CB)];                                                       \
    __builtin_amdgcn_global_load_lds(                                               \
        (const __attribute__((address_space(1))) unsigned int*)(pA0 + (KT) * BK),   \
        (__attribute__((address_space(3))) unsigned int*)(sAb + (ws * 2 + 0) * 512),\
        16, 0, 0);                                                                  \
    __builtin_amdgcn_global_load_lds(                                               \
        (const __attribute__((address_space(1))) unsigned int*)(pA1 + (KT) * BK),   \
        (__attribute__((address_space(3))) unsigned int*)(sAb + (ws * 2 + 1) * 512),\
        16, 0, 0);                                                                  \
} while (0)

#define STAGE_B(CB, KT) do {                                                        \
    u16* sBb = u.st.sB[(CB)];                                                       \
    _Pragma("unroll")                                                               \
    for (int q = 0; q < 3; ++q) {                                                   \
        const int idxq = ws * 3 + q;                                                \
        __builtin_amdgcn_global_load_lds(                                           \
            (const __attribute__((address_space(1))) unsigned int*)(gaB0 + dB[q] + (KT) * BK), \
            (__attribute__((address_space(3))) unsigned int*)(sBb + (idxq >> 2) * (BN * BK) + (idxq & 3) * 512), \
            16, 0, 0);                                                              \
    }                                                                               \
} while (0)

    f32x4 acc[3][4][2] = {};

    // ---- prologue: stage tile 0 into buf 0 ----
    STAGE_A(0, 0);
    STAGE_B(0, 0);

#define KSTEP(KT) do {                                                              \
    constexpr int cur_ = (KT) & 1;                                                  \
    constexpr int nxt_ = cur_ ^ 1;                                                  \
    if ((KT) < 15) {                                                                \
        STAGE_A(nxt_, (KT) + 1);                                                    \
        STAGE_B(nxt_, (KT) + 1);                                                    \
        asm volatile("s_waitcnt vmcnt(5)" ::: "memory");                            \
    } else {                                                                        \
        asm volatile("s_waitcnt vmcnt(0)" ::: "memory");                            \
    }                                                                               \
    __builtin_amdgcn_sched_barrier(0);                                              \
    __builtin_amdgcn_s_barrier();                                                   \
    {                                                                               \
        const u16* sAb = u.st.sA[cur_];                                             \
        const u16* sBb = u.st.sB[cur_];                                             \
        bf16x8 af[4];                                                               \
        _Pragma("unroll")                                                           \
        for (int m = 0; m < 4; m++)                                                 \
            af[m] = *reinterpret_cast<const bf16x8*>(sAb + offA0 + m * 16 * BK);    \
        __builtin_amdgcn_s_setprio(1);                                              \
        _Pragma("unroll")                                                           \
        for (int g = 0; g < 3; g++) {                                               \
            const u16* sbg = sBb + g * (BN * BK);                                   \
            bf16x8 b0 = *reinterpret_cast<const bf16x8*>(sbg + offB0);              \
            bf16x8 b1 = *reinterpret_cast<const bf16x8*>(sbg + offB0 + 16 * BK);    \
            _Pragma("unroll")                                                       \
            for (int m = 0; m < 4; m++) {                                           \
                acc[g][m][0] = __builtin_amdgcn_mfma_f32_16x16x32_bf16(af[m], b0, acc[g][m][0], 0, 0, 0); \
                acc[g][m][1] = __builtin_amdgcn_mfma_f32_16x16x32_bf16(af[m], b1, acc[g][m][1], 0, 0, 0); \
            }                                                                       \
        }                                                                           \
        __builtin_amdgcn_s_setprio(0);                                              \
    }                                                                               \
    if ((KT) < 15) {                                                                \
        __builtin_amdgcn_sched_barrier(0);                                          \
        __builtin_amdgcn_s_barrier();                                               \
    }                                                                               \
} while (0)

    KSTEP(0);  KSTEP(1);  KSTEP(2);  KSTEP(3);
    KSTEP(4);  KSTEP(5);  KSTEP(6);  KSTEP(7);
    KSTEP(8);  KSTEP(9);  KSTEP(10); KSTEP(11);
    KSTEP(12); KSTEP(13); KSTEP(14); KSTEP(15);
#undef KSTEP
#undef STAGE_B
#undef STAGE_A

    __syncthreads();   // full drain before LDS overlay reuse

    // ---- epilogue: activations -> transposed LDS ----
    // 16x16 C/D layout: col = lane&15, row = (lane>>4)*4 + j
    // bf16 packing via v_cvt_pk_bf16_f32 (RNE, proven R8).
    const int rbase = (lane >> 4) * 4;
#pragma unroll
    for (int n = 0; n < 2; n++) {
        const int cl = wc * 32 + n * 16 + fr;     // local h col 0..63
        const int hg = n0 + cl;
        const float bi_ = b_i[hg];
        const float bfv = b_f[hg];
        const float bg_ = b_g[hg];
#pragma unroll
        for (int m = 0; m < 4; m++) {
            const int rr0 = wr * 64 + m * 16 + rbase;   // time row 0..127, mult of 4
            float fv[4], pv[4];
#pragma unroll
            for (int jj = 0; jj < 4; jj++) {
                const float fi = sigm(acc[0][m][n][jj] + bi_);
                const float ff = sigm(acc[1][m][n][jj] + bfv);
                const float fg = tanh_(acc[2][m][n][jj] + bg_);
                fv[jj] = ff;
                pv[jj] = fi * fg;
            }
            unsigned int f01, f23, p01, p23;
            asm("v_cvt_pk_bf16_f32 %0, %1, %2" : "=v"(f01) : "v"(fv[0]), "v"(fv[1]));
            asm("v_cvt_pk_bf16_f32 %0, %1, %2" : "=v"(f23) : "v"(fv[2]), "v"(fv[3]));
            asm("v_cvt_pk_bf16_f32 %0, %1, %2" : "=v"(p01) : "v"(pv[0]), "v"(pv[1]));
            asm("v_cvt_pk_bf16_f32 %0, %1, %2" : "=v"(p23) : "v"(pv[2]), "v"(pv[3]));
            uint2 fw; fw.x = f01; fw.y = f23;
            uint2 pw; pw.x = p01; pw.y = p23;
            *reinterpret_cast<uint2*>(&u.sc.Ft[cl][rr0]) = fw;
            *reinterpret_cast<uint2*>(&u.sc.Pt[cl][rr0]) = pw;
        }
    }
    __syncthreads();

    // ---- in-LDS chunk scan: 64 h cols x 4 quarter-segments of 32 t ----
    {
        const int h = tid & 63;
        const int q = tid >> 6;
        const int t0 = q * 32;
        float a = 1.0f, v = 0.0f;
#pragma unroll
        for (int kk = 0; kk < 8; kk++) {
            s16x4 fv = *reinterpret_cast<const s16x4*>(&u.sc.Ft[h][t0 + kk * 4]);
            s16x4 pv4 = *reinterpret_cast<const s16x4*>(&u.sc.Pt[h][t0 + kk * 4]);
#pragma unroll
            for (int e = 0; e < 4; e++) {
                const float f = bf2f((u16)fv[e]);
                const float p = bf2f((u16)pv4[e]);
                v = f * v + p;
                a *= f;
            }
        }
        u.sc.pa[tid] = a;
        u.sc.pv[tid] = v;
    }
    __syncthreads();

    if (tid < 64) {
        float Aacc = u.sc.pa[tid];
        float Vacc = u.sc.pv[tid];
#pragma unroll
        for (int q = 1; q < 4; q++) {
            const float aq = u.sc.pa[q * 64 + tid];
            const float vq = u.sc.pv[q * 64 + tid];
            Vacc = aq * Vacc + vq;
            Aacc *= aq;
        }
        // layout: [b][chunk][h] = [mtile][h]  (mtile = b*16 + chunk)
        const size_t o = (size_t)mtile * DH + n0 + tid;
        Ach[o] = Aacc;
        Vch[o] = Vacc;
    }
}

// ---------------- finalize stage 1: c-combine + o-gate GEMV -> h_val (R4-proven) ----------------
__global__ __launch_bounds__(256)
void finalize_h(const float* __restrict__ Ach, const float* __restrict__ Vch,
                const float* __restrict__ x, const float* __restrict__ Wo,
                const float* __restrict__ bo, float* __restrict__ hval) {
    __shared__ float woT[8][512];    // 16KB
    __shared__ float xl[32][129];    // 16.5KB, pad -> bank (b + k) % 32
    const int tid = threadIdx.x;
    const int h0 = blockIdx.x * 8;
    const int hloc = tid >> 5;       // 0..7
    const int b = tid & 31;          // 0..31
    const int h = h0 + hloc;

    // stage Wo rows h0..h0+7
    {
        const int r = tid >> 5, q = tid & 31;
#pragma unroll
        for (int m = 0; m < 4; m++) {
            float4 v = reinterpret_cast<const float4*>(Wo + (size_t)(h0 + r) * DI)[q + 32 * m];
            *reinterpret_cast<float4*>(&woT[r][4 * (q + 32 * m)]) = v;
        }
    }

    // chunk-combine c for (b, h): time-ordered over 16 chunks
    float c = 0.0f;
#pragma unroll
    for (int jj = 0; jj < NCHUNK; jj++) {
        const size_t o = ((size_t)(b * NCHUNK + jj)) * DH + h;
        c = Ach[o] * c + Vch[o];
    }

    // dot(Wo[h], x[b, T-1, :]) in 4 chunks of 128 k
    float dot = 0.0f;
    for (int kc = 0; kc < 4; kc++) {
        __syncthreads();
        {   // stage x_last[:, kc*128 .. +127]
            const int r = tid >> 3, s = tid & 7;
            const float* xr = x + ((size_t)r * NT + (NT - 1)) * DI + kc * 128;
#pragma unroll
            for (int m = 0; m < 4; m++) {
                float4 v = reinterpret_cast<const float4*>(xr)[s + 8 * m];
                const int cbase = 4 * (s + 8 * m);
                xl[r][cbase + 0] = v.x; xl[r][cbase + 1] = v.y;
                xl[r][cbase + 2] = v.z; xl[r][cbase + 3] = v.w;
            }
        }
        __syncthreads();
#pragma unroll 8
        for (int k = 0; k < 128; k++)
            dot += woT[hloc][kc * 128 + k] * xl[b][k];
    }

    const float og = sigm(dot + bo[h]);
    hval[(size_t)b * DH + h] = og * tanh_(c);
}

// ---------------- finalize stage 2: FC (R4-proven) ----------------
__global__ __launch_bounds__(256)
void finalize_fc2(const float* __restrict__ hval, const float* __restrict__ Wfc,
                  const float* __restrict__ bfc, float* __restrict__ out) {
    __shared__ float wf[8][512];     // 16KB
    __shared__ float hl[32][129];    // 16.5KB
    const int tid = threadIdx.x;
    const int o0 = blockIdx.x * 8;
    const int oloc = tid >> 5;       // 0..7
    const int b = tid & 31;          // 0..31

    {
        const int r = tid >> 5, q = tid & 31;
#pragma unroll
        for (int m = 0; m < 4; m++) {
            float4 v = reinterpret_cast<const float4*>(Wfc + (size_t)(o0 + r) * DH)[q + 32 * m];
            *reinterpret_cast<float4*>(&wf[r][4 * (q + 32 * m)]) = v;
        }
    }

    float acc = 0.0f;
    for (int kc = 0; kc < 4; kc++) {
        __syncthreads();
        {
            const int r = tid >> 3, s = tid & 7;
            const float* hr = hval + (size_t)r * DH + kc * 128;
#pragma unroll
            for (int m = 0; m < 4; m++) {
                float4 v = reinterpret_cast<const float4*>(hr)[s + 8 * m];
                const int cbase = 4 * (s + 8 * m);
                hl[r][cbase + 0] = v.x; hl[r][cbase + 1] = v.y;
                hl[r][cbase + 2] = v.z; hl[r][cbase + 3] = v.w;
            }
        }
        __syncthreads();
#pragma unroll 8
        for (int k = 0; k < 128; k++)
            acc += wf[oloc][kc * 128 + k] * hl[b][k];
    }

    out[b * DOUT + (o0 + oloc)] = acc + bfc[o0 + oloc];
}

extern "C" void kernel_launch(void* const* d_in, const int* in_sizes, int n_in,
                              void* d_out, int out_size, void* d_ws, size_t ws_size,
                              hipStream_t stream) {
    const float* x    = (const float*)d_in[0];
    const float* W_i  = (const float*)d_in[1];
    const float* b_i  = (const float*)d_in[2];
    const float* W_f  = (const float*)d_in[3];
    const float* b_f  = (const float*)d_in[4];
    const float* W_g  = (const float*)d_in[5];
    const float* b_g  = (const float*)d_in[6];
    const float* W_o  = (const float*)d_in[7];
    const float* b_o  = (const float*)d_in[8];
    const float* W_fc = (const float*)d_in[9];
    const float* b_fc = (const float*)d_in[10];
    float* out = (float*)d_out;

    char* ws = (char*)d_ws;
    const size_t XBF_BYTES = (size_t)MTOT * DI * 2;        // 67,108,864
    const size_t WBF_BYTES = (size_t)3 * DH * DI * 2;      //  1,572,864
    const size_t AV_BYTES  = (size_t)MTOT / CLEN * DH * 4; //  1,048,576 each

    u16* xbf   = (u16*)ws;
    u16* wbf   = (u16*)(ws + XBF_BYTES);
    float* Ach = (float*)(ws + XBF_BYTES + WBF_BYTES);
    float* Vch = (float*)(ws + XBF_BYTES + WBF_BYTES + AV_BYTES);
    // h_val aliases the wbf region (dead after the gemm) -> NEED unchanged.
    float* hval = (float*)(ws + XBF_BYTES);

    cvt_all2<<<8960, 256, 0, stream>>>(x, W_i, W_f, W_g, xbf, wbf);

    gate_gemm_scan<<<4096, 256, 0, stream>>>(xbf, wbf, b_i, b_f, b_g, Ach, Vch);

    finalize_h<<<64, 256, 0, stream>>>(Ach, Vch, x, W_o, b_o, hval);

    finalize_fc2<<<32, 256, 0, stream>>>(hval, W_fc, b_fc, out);
}

// Round 10
// 170.538 us; speedup vs baseline: 1.4789x; 1.4789x over previous
//
#include <hip/hip_runtime.h>
#include <stdint.h>

#define DI 512
#define DH 512
#define DOUT 256
#define NB 32
#define NT 2048
#define MTOT (NB*NT)   // 65536
#define NCHUNK 16
#define CLEN 128       // NT / NCHUNK
#define BM 128
#define BN 64
#define BK 32

typedef unsigned short u16;
typedef __attribute__((ext_vector_type(8))) short bf16x8;
typedef __attribute__((ext_vector_type(4))) short s16x4;
typedef __attribute__((ext_vector_type(4))) float f32x4;

__device__ __forceinline__ u16 f2bf(float f) {
    union { float f; unsigned int u; } c; c.f = f;
    unsigned int u = c.u;
    u += 0x7fffu + ((u >> 16) & 1u);   // RNE
    return (u16)(u >> 16);
}
__device__ __forceinline__ float bf2f(u16 h) {
    union { unsigned int u; float f; } c; c.u = ((unsigned int)h) << 16;
    return c.f;
}
__device__ __forceinline__ float sigm(float x) { return 1.0f / (1.0f + __expf(-x)); }
__device__ __forceinline__ float tanh_(float x) { return 1.0f - 2.0f / (__expf(2.0f * x) + 1.0f); }

// ---------------- one-shot cvt: x (128MB) + 3 W matrices -> bf16 ----------------
// x: 8192 blocks x 256 thr x 2 iters (2x waves vs 4096x4 for latency hiding on
// the 2-load/1-store stream). W: 768 extra blocks. Floor ~31us.
__global__ __launch_bounds__(256)
void cvt_all2(const float* __restrict__ X, const float* __restrict__ w0,
              const float* __restrict__ w1, const float* __restrict__ w2,
              u16* __restrict__ xbf, u16* __restrict__ wbf) {
    const int bid = blockIdx.x;
    const int tid = threadIdx.x;
    if (bid < 8192) {
        const int idx = bid * 256 + tid;           // 0..2097151
        const float4* s4 = reinterpret_cast<const float4*>(X);
        uint4* d4 = reinterpret_cast<uint4*>(xbf);
#pragma unroll
        for (int it = 0; it < 2; ++it) {
            const int j = it * 2097152 + idx;      // uint4 index < 4194304
            float4 v0 = s4[2 * j];
            float4 v1 = s4[2 * j + 1];
            unsigned int p0, p1, p2, p3;
            asm("v_cvt_pk_bf16_f32 %0, %1, %2" : "=v"(p0) : "v"(v0.x), "v"(v0.y));
            asm("v_cvt_pk_bf16_f32 %0, %1, %2" : "=v"(p1) : "v"(v0.z), "v"(v0.w));
            asm("v_cvt_pk_bf16_f32 %0, %1, %2" : "=v"(p2) : "v"(v1.x), "v"(v1.y));
            asm("v_cvt_pk_bf16_f32 %0, %1, %2" : "=v"(p3) : "v"(v1.z), "v"(v1.w));
            uint4 o; o.x = p0; o.y = p1; o.z = p2; o.w = p3;
            d4[j] = o;
        }
    } else {
        const int gid = (bid - 8192) * 256 + tid;  // 0..196607
        const int wsel = gid >> 16;                // per-W float4 count = 65536
        const int i = gid & 65535;
        const float* src = (wsel == 0) ? w0 : (wsel == 1) ? w1 : w2;
        float4 v = reinterpret_cast<const float4*>(src)[i];
        ushort4 o;
        o.x = f2bf(v.x); o.y = f2bf(v.y); o.z = f2bf(v.z); o.w = f2bf(v.w);
        reinterpret_cast<ushort4*>(wbf + (size_t)wsel * DH * DI)[i] = o;
    }
}

// ---------------- gate GEMM + activations + chunk scan (R8-proven, 121.4us) ----------------
// __launch_bounds__(256, 3): R9 proved 4 waves/SIMD caps regs at ~128 -> the
// ~180-reg kernel spills catastrophically (VGPR 64, WRITE_SIZE 342GB). 3
// blocks/CU is the register-file ceiling for this acc footprint. K-loop,
// staging swizzles, counted vmcnt(5), 2-barrier discipline all R8-verbatim.
__global__ __launch_bounds__(256, 3)
void gate_gemm_scan(const u16* __restrict__ Xbf, const u16* __restrict__ W,
                    const float* __restrict__ b_i, const float* __restrict__ b_f,
                    const float* __restrict__ b_g,
                    float* __restrict__ Ach, float* __restrict__ Vch) {
    __shared__ __align__(16) union {
        struct { u16 sA[2][BM * BK]; u16 sB[2][3 * BN * BK]; } st;   // 16KB + 24KB = 40KB
        struct { u16 Ft[BN][132]; u16 Pt[BN][132]; float pa[256]; float pv[256]; } sc;
    } u;

    // XCD-aware swizzle: blocks with bid%8==k land on XCD k and cover one
    // mtile's 8 ntiles consecutively -> A L2-shared within the XCD.
    const int bid0 = blockIdx.x;
    const int swz = (bid0 & 7) * 512 + (bid0 >> 3);
    const int mtile = swz >> 3;          // 0..511  (b*16 + chunk)
    const int ntile = swz & 7;           // 0..7
    const int m0 = mtile * BM;
    const int n0 = ntile * BN;

    const int tid = threadIdx.x;
    const int lane = tid & 63;
    const int ws = __builtin_amdgcn_readfirstlane(tid >> 6);   // scalar wave id
    const int wr = ws >> 1;              // M offset wr*64
    const int wc = ws & 1;               // N offset wc*32

    const int srow = lane >> 2;          // staging: row within 16-row chunk
    const int slot = lane & 3;           // staging: 16B slot within 64B row
    const int fr = lane & 15;
    const int khalf = lane >> 4;         // 0..3

    // A bf16 source: pre-swizzled per-lane addr; LDS image matches the proven
    // swizzled layout, so frag reads are unchanged.
    const int rlA = ws * 32 + srow;
    const int swzslot = slot ^ ((rlA >> 1) & 3);       // same for row+16
    const u16* pA0 = Xbf + (size_t)(m0 + rlA) * DI + swzslot * 8;
    const u16* pA1 = pA0 + (size_t)16 * DI;

    // B staging base (q=0) + wave-uniform deltas for q=1,2 (proven).
    const int idx0 = ws * 3;
    const int g0 = idx0 >> 2, cc0 = idx0 & 3;
    const int rlB0 = cc0 * 16 + srow;
    const u16* gaB0 = W + (size_t)g0 * DH * DI + (size_t)(n0 + rlB0) * DI
                    + ((slot ^ ((rlB0 >> 1) & 3)) * 8);
    int dB[3];
    dB[0] = 0;
#pragma unroll
    for (int q = 1; q < 3; ++q) {
        const int idxq = idx0 + q;
        const int gq = idxq >> 2, ccq = idxq & 3;
        dB[q] = __builtin_amdgcn_readfirstlane((gq - g0) * (DH * DI) + (ccq - cc0) * 16 * DI);
    }

    // per-lane LDS read offsets (u16 units), swizzled slot (proven, 0-conflict)
    const int rA = wr * 64 + fr;
    const int offA0 = rA * BK + ((khalf ^ ((rA >> 1) & 3)) * 8);
    const int rB = wc * 32 + fr;
    const int offB0 = rB * BK + ((khalf ^ ((rB >> 1) & 3)) * 8);

#define STAGE_A(CB, KT) do {                                                        \
    u16* sAb = u.st.sA[(CB)];                                                       \
    __builtin_amdgcn_global_load_lds(                                               \
        (const __attribute__((address_space(1))) unsigned int*)(pA0 + (KT) * BK),   \
        (__attribute__((address_space(3))) unsigned int*)(sAb + (ws * 2 + 0) * 512),\
        16, 0, 0);                                                                  \
    __builtin_amdgcn_global_load_lds(                                               \
        (const __attribute__((address_space(1))) unsigned int*)(pA1 + (KT) * BK),   \
        (__attribute__((address_space(3))) unsigned int*)(sAb + (ws * 2 + 1) * 512),\
        16, 0, 0);                                                                  \
} while (0)

#define STAGE_B(CB, KT) do {                                                        \
    u16* sBb = u.st.sB[(CB)];                                                       \
    _Pragma("unroll")                                                               \
    for (int q = 0; q < 3; ++q) {                                                   \
        const int idxq = ws * 3 + q;                                                \
        __builtin_amdgcn_global_load_lds(                                           \
            (const __attribute__((address_space(1))) unsigned int*)(gaB0 + dB[q] + (KT) * BK), \
            (__attribute__((address_space(3))) unsigned int*)(sBb + (idxq >> 2) * (BN * BK) + (idxq & 3) * 512), \
            16, 0, 0);                                                              \
    }                                                                               \
} while (0)

    f32x4 acc[3][4][2] = {};

    // ---- prologue: stage tile 0 into buf 0 ----
    STAGE_A(0, 0);
    STAGE_B(0, 0);

#define KSTEP(KT) do {                                                              \
    constexpr int cur_ = (KT) & 1;                                                  \
    constexpr int nxt_ = cur_ ^ 1;                                                  \
    if ((KT) < 15) {                                                                \
        STAGE_A(nxt_, (KT) + 1);                                                    \
        STAGE_B(nxt_, (KT) + 1);                                                    \
        asm volatile("s_waitcnt vmcnt(5)" ::: "memory");                            \
    } else {                                                                        \
        asm volatile("s_waitcnt vmcnt(0)" ::: "memory");                            \
    }                                                                               \
    __builtin_amdgcn_sched_barrier(0);                                              \
    __builtin_amdgcn_s_barrier();                                                   \
    {                                                                               \
        const u16* sAb = u.st.sA[cur_];                                             \
        const u16* sBb = u.st.sB[cur_];                                             \
        bf16x8 af[4];                                                               \
        _Pragma("unroll")                                                           \
        for (int m = 0; m < 4; m++)                                                 \
            af[m] = *reinterpret_cast<const bf16x8*>(sAb + offA0 + m * 16 * BK);    \
        __builtin_amdgcn_s_setprio(1);                                              \
        _Pragma("unroll")                                                           \
        for (int g = 0; g < 3; g++) {                                               \
            const u16* sbg = sBb + g * (BN * BK);                                   \
            bf16x8 b0 = *reinterpret_cast<const bf16x8*>(sbg + offB0);              \
            bf16x8 b1 = *reinterpret_cast<const bf16x8*>(sbg + offB0 + 16 * BK);    \
            _Pragma("unroll")                                                       \
            for (int m = 0; m < 4; m++) {                                           \
                acc[g][m][0] = __builtin_amdgcn_mfma_f32_16x16x32_bf16(af[m], b0, acc[g][m][0], 0, 0, 0); \
                acc[g][m][1] = __builtin_amdgcn_mfma_f32_16x16x32_bf16(af[m], b1, acc[g][m][1], 0, 0, 0); \
            }                                                                       \
        }                                                                           \
        __builtin_amdgcn_s_setprio(0);                                              \
    }                                                                               \
    if ((KT) < 15) {                                                                \
        __builtin_amdgcn_sched_barrier(0);                                          \
        __builtin_amdgcn_s_barrier();                                               \
    }                                                                               \
} while (0)

    KSTEP(0);  KSTEP(1);  KSTEP(2);  KSTEP(3);
    KSTEP(4);  KSTEP(5);  KSTEP(6);  KSTEP(7);
    KSTEP(8);  KSTEP(9);  KSTEP(10); KSTEP(11);
    KSTEP(12); KSTEP(13); KSTEP(14); KSTEP(15);
#undef KSTEP
#undef STAGE_B
#undef STAGE_A

    __syncthreads();   // full drain before LDS overlay reuse

    // ---- epilogue: activations -> transposed LDS ----
    // 16x16 C/D layout: col = lane&15, row = (lane>>4)*4 + j
    // bf16 packing via v_cvt_pk_bf16_f32 (RNE, proven R8).
    const int rbase = (lane >> 4) * 4;
#pragma unroll
    for (int n = 0; n < 2; n++) {
        const int cl = wc * 32 + n * 16 + fr;     // local h col 0..63
        const int hg = n0 + cl;
        const float bi_ = b_i[hg];
        const float bfv = b_f[hg];
        const float bg_ = b_g[hg];
#pragma unroll
        for (int m = 0; m < 4; m++) {
            const int rr0 = wr * 64 + m * 16 + rbase;   // time row 0..127, mult of 4
            float fv[4], pv[4];
#pragma unroll
            for (int jj = 0; jj < 4; jj++) {
                const float fi = sigm(acc[0][m][n][jj] + bi_);
                const float ff = sigm(acc[1][m][n][jj] + bfv);
                const float fg = tanh_(acc[2][m][n][jj] + bg_);
                fv[jj] = ff;
                pv[jj] = fi * fg;
            }
            unsigned int f01, f23, p01, p23;
            asm("v_cvt_pk_bf16_f32 %0, %1, %2" : "=v"(f01) : "v"(fv[0]), "v"(fv[1]));
            asm("v_cvt_pk_bf16_f32 %0, %1, %2" : "=v"(f23) : "v"(fv[2]), "v"(fv[3]));
            asm("v_cvt_pk_bf16_f32 %0, %1, %2" : "=v"(p01) : "v"(pv[0]), "v"(pv[1]));
            asm("v_cvt_pk_bf16_f32 %0, %1, %2" : "=v"(p23) : "v"(pv[2]), "v"(pv[3]));
            uint2 fw; fw.x = f01; fw.y = f23;
            uint2 pw; pw.x = p01; pw.y = p23;
            *reinterpret_cast<uint2*>(&u.sc.Ft[cl][rr0]) = fw;
            *reinterpret_cast<uint2*>(&u.sc.Pt[cl][rr0]) = pw;
        }
    }
    __syncthreads();

    // ---- in-LDS chunk scan: 64 h cols x 4 quarter-segments of 32 t ----
    {
        const int h = tid & 63;
        const int q = tid >> 6;
        const int t0 = q * 32;
        float a = 1.0f, v = 0.0f;
#pragma unroll
        for (int kk = 0; kk < 8; kk++) {
            s16x4 fv = *reinterpret_cast<const s16x4*>(&u.sc.Ft[h][t0 + kk * 4]);
            s16x4 pv4 = *reinterpret_cast<const s16x4*>(&u.sc.Pt[h][t0 + kk * 4]);
#pragma unroll
            for (int e = 0; e < 4; e++) {
                const float f = bf2f((u16)fv[e]);
                const float p = bf2f((u16)pv4[e]);
                v = f * v + p;
                a *= f;
            }
        }
        u.sc.pa[tid] = a;
        u.sc.pv[tid] = v;
    }
    __syncthreads();

    if (tid < 64) {
        float Aacc = u.sc.pa[tid];
        float Vacc = u.sc.pv[tid];
#pragma unroll
        for (int q = 1; q < 4; q++) {
            const float aq = u.sc.pa[q * 64 + tid];
            const float vq = u.sc.pv[q * 64 + tid];
            Vacc = aq * Vacc + vq;
            Aacc *= aq;
        }
        // layout: [b][chunk][h] = [mtile][h]  (mtile = b*16 + chunk)
        const size_t o = (size_t)mtile * DH + n0 + tid;
        Ach[o] = Aacc;
        Vch[o] = Vacc;
    }
}

// ---------------- finalize stage 1: c-combine + o-gate GEMV -> h_val (R4-proven) ----------------
__global__ __launch_bounds__(256)
void finalize_h(const float* __restrict__ Ach, const float* __restrict__ Vch,
                const float* __restrict__ x, const float* __restrict__ Wo,
                const float* __restrict__ bo, float* __restrict__ hval) {
    __shared__ float woT[8][512];    // 16KB
    __shared__ float xl[32][129];    // 16.5KB, pad -> bank (b + k) % 32
    const int tid = threadIdx.x;
    const int h0 = blockIdx.x * 8;
    const int hloc = tid >> 5;       // 0..7
    const int b = tid & 31;          // 0..31
    const int h = h0 + hloc;

    // stage Wo rows h0..h0+7
    {
        const int r = tid >> 5, q = tid & 31;
#pragma unroll
        for (int m = 0; m < 4; m++) {
            float4 v = reinterpret_cast<const float4*>(Wo + (size_t)(h0 + r) * DI)[q + 32 * m];
            *reinterpret_cast<float4*>(&woT[r][4 * (q + 32 * m)]) = v;
        }
    }

    // chunk-combine c for (b, h): time-ordered over 16 chunks
    float c = 0.0f;
#pragma unroll
    for (int jj = 0; jj < NCHUNK; jj++) {
        const size_t o = ((size_t)(b * NCHUNK + jj)) * DH + h;
        c = Ach[o] * c + Vch[o];
    }

    // dot(Wo[h], x[b, T-1, :]) in 4 chunks of 128 k
    float dot = 0.0f;
    for (int kc = 0; kc < 4; kc++) {
        __syncthreads();
        {   // stage x_last[:, kc*128 .. +127]
            const int r = tid >> 3, s = tid & 7;
            const float* xr = x + ((size_t)r * NT + (NT - 1)) * DI + kc * 128;
#pragma unroll
            for (int m = 0; m < 4; m++) {
                float4 v = reinterpret_cast<const float4*>(xr)[s + 8 * m];
                const int cbase = 4 * (s + 8 * m);
                xl[r][cbase + 0] = v.x; xl[r][cbase + 1] = v.y;
                xl[r][cbase + 2] = v.z; xl[r][cbase + 3] = v.w;
            }
        }
        __syncthreads();
#pragma unroll 8
        for (int k = 0; k < 128; k++)
            dot += woT[hloc][kc * 128 + k] * xl[b][k];
    }

    const float og = sigm(dot + bo[h]);
    hval[(size_t)b * DH + h] = og * tanh_(c);
}

// ---------------- finalize stage 2: FC (R4-proven) ----------------
__global__ __launch_bounds__(256)
void finalize_fc2(const float* __restrict__ hval, const float* __restrict__ Wfc,
                  const float* __restrict__ bfc, float* __restrict__ out) {
    __shared__ float wf[8][512];     // 16KB
    __shared__ float hl[32][129];    // 16.5KB
    const int tid = threadIdx.x;
    const int o0 = blockIdx.x * 8;
    const int oloc = tid >> 5;       // 0..7
    const int b = tid & 31;          // 0..31

    {
        const int r = tid >> 5, q = tid & 31;
#pragma unroll
        for (int m = 0; m < 4; m++) {
            float4 v = reinterpret_cast<const float4*>(Wfc + (size_t)(o0 + r) * DH)[q + 32 * m];
            *reinterpret_cast<float4*>(&wf[r][4 * (q + 32 * m)]) = v;
        }
    }

    float acc = 0.0f;
    for (int kc = 0; kc < 4; kc++) {
        __syncthreads();
        {
            const int r = tid >> 3, s = tid & 7;
            const float* hr = hval + (size_t)r * DH + kc * 128;
#pragma unroll
            for (int m = 0; m < 4; m++) {
                float4 v = reinterpret_cast<const float4*>(hr)[s + 8 * m];
                const int cbase = 4 * (s + 8 * m);
                hl[r][cbase + 0] = v.x; hl[r][cbase + 1] = v.y;
                hl[r][cbase + 2] = v.z; hl[r][cbase + 3] = v.w;
            }
        }
        __syncthreads();
#pragma unroll 8
        for (int k = 0; k < 128; k++)
            acc += wf[oloc][kc * 128 + k] * hl[b][k];
    }

    out[b * DOUT + (o0 + oloc)] = acc + bfc[o0 + oloc];
}

extern "C" void kernel_launch(void* const* d_in, const int* in_sizes, int n_in,
                              void* d_out, int out_size, void* d_ws, size_t ws_size,
                              hipStream_t stream) {
    const float* x    = (const float*)d_in[0];
    const float* W_i  = (const float*)d_in[1];
    const float* b_i  = (const float*)d_in[2];
    const float* W_f  = (const float*)d_in[3];
    const float* b_f  = (const float*)d_in[4];
    const float* W_g  = (const float*)d_in[5];
    const float* b_g  = (const float*)d_in[6];
    const float* W_o  = (const float*)d_in[7];
    const float* b_o  = (const float*)d_in[8];
    const float* W_fc = (const float*)d_in[9];
    const float* b_fc = (const float*)d_in[10];
    float* out = (float*)d_out;

    char* ws = (char*)d_ws;
    const size_t XBF_BYTES = (size_t)MTOT * DI * 2;        // 67,108,864
    const size_t WBF_BYTES = (size_t)3 * DH * DI * 2;      //  1,572,864
    const size_t AV_BYTES  = (size_t)MTOT / CLEN * DH * 4; //  1,048,576 each

    u16* xbf   = (u16*)ws;
    u16* wbf   = (u16*)(ws + XBF_BYTES);
    float* Ach = (float*)(ws + XBF_BYTES + WBF_BYTES);
    float* Vch = (float*)(ws + XBF_BYTES + WBF_BYTES + AV_BYTES);
    // h_val aliases the wbf region (dead after the gemm) -> NEED unchanged.
    float* hval = (float*)(ws + XBF_BYTES);

    cvt_all2<<<8960, 256, 0, stream>>>(x, W_i, W_f, W_g, xbf, wbf);

    gate_gemm_scan<<<4096, 256, 0, stream>>>(xbf, wbf, b_i, b_f, b_g, Ach, Vch);

    finalize_h<<<64, 256, 0, stream>>>(Ach, Vch, x, W_o, b_o, hval);

    finalize_fc2<<<32, 256, 0, stream>>>(hval, W_fc, b_fc, out);
}